// Round 1
// baseline (23056.879 us; speedup 1.0000x reference)
//
#include <hip/hip_runtime.h>
#include <stdint.h>

typedef unsigned short u16;
typedef __attribute__((ext_vector_type(8))) short short8;
typedef __attribute__((ext_vector_type(4))) float f32x4;

__device__ __forceinline__ u16 f2bf(float f) {
  union { float f; uint32_t u; } x; x.f = f;
  uint32_t u = x.u;
  uint32_t r = (u + 0x7fffu + ((u >> 16) & 1u)) >> 16;
  return (u16)r;
}
__device__ __forceinline__ float bf2f(u16 h) {
  union { uint32_t u; float f; } x; x.u = ((uint32_t)h) << 16;
  return x.f;
}

#define NX 16777216   // 32*512*1024
#define NWI 4194304   // 4096*1024

// ---------------- prep: fp32 -> bf16 for x, Wi; bias = bi + bh ----------------
__global__ __launch_bounds__(256) void prep_kernel(
    const float* __restrict__ x, const float* __restrict__ Wi,
    const float* __restrict__ bi, const float* __restrict__ bh,
    u16* __restrict__ xbf, u16* __restrict__ wibf, float* __restrict__ bias) {
  int tid = blockIdx.x * blockDim.x + threadIdx.x;
  int stride = gridDim.x * blockDim.x;
  const int nx4 = NX / 4, nw4 = NWI / 4;
  for (int i = tid; i < nx4 + nw4; i += stride) {
    float4 v = (i < nx4) ? ((const float4*)x)[i] : ((const float4*)Wi)[i - nx4];
    ushort4 o;
    o.x = f2bf(v.x); o.y = f2bf(v.y); o.z = f2bf(v.z); o.w = f2bf(v.w);
    if (i < nx4) ((ushort4*)xbf)[i] = o; else ((ushort4*)wibf)[i - nx4] = o;
  }
  for (int i = tid; i < 4096; i += stride) bias[i] = bi[i] + bh[i];
}

// ---------------- x_proj GEMM: D[m][n] = sum_k A[m][k]*Wi[n][k] + bias[n] -----
// m = t*32 + b  (xproj layout [T][B][4H], bf16 out)
__global__ __launch_bounds__(256) void gemm_xproj(
    const u16* __restrict__ xbf, const u16* __restrict__ wibf,
    const float* __restrict__ bias, u16* __restrict__ xproj) {
  __shared__ __align__(16) short Als[8192];  // 1024 16B chunks, [k8][m] XOR-swizzled
  __shared__ __align__(16) short Bls[8192];
  const int tid = threadIdx.x;
  const int lane = tid & 63;
  const int wv = tid >> 6;
  const int nb = blockIdx.x, mb = blockIdx.y;

  int offA[4], offB[4], ldsO[4];
#pragma unroll
  for (int i = 0; i < 4; ++i) {
    int s = i * 256 + tid;
    int m = s >> 3, k8 = s & 7;
    int mg = mb * 128 + m;                 // row of xproj = t*32+b
    offA[i] = ((mg & 31) * 512 + (mg >> 5)) * 1024 + k8 * 8;  // x[b][t][k8*8]
    int ng = nb * 128 + m;
    offB[i] = ng * 1024 + k8 * 8;
    ldsO[i] = (k8 * 128 + (m ^ k8)) * 8;
  }

  f32x4 acc[4][4];
#pragma unroll
  for (int a = 0; a < 4; ++a)
#pragma unroll
    for (int b = 0; b < 4; ++b) acc[a][b] = {0.f, 0.f, 0.f, 0.f};

  const int wm = wv >> 1, wn = wv & 1;
  const int q = lane >> 4, l15 = lane & 15;

  for (int k0 = 0; k0 < 1024; k0 += 64) {
    __syncthreads();
#pragma unroll
    for (int i = 0; i < 4; ++i) {
      short8 va = *(const short8*)(xbf + offA[i] + k0);
      short8 vb = *(const short8*)(wibf + offB[i] + k0);
      *(short8*)&Als[ldsO[i]] = va;
      *(short8*)&Bls[ldsO[i]] = vb;
    }
    __syncthreads();
#pragma unroll
    for (int kk = 0; kk < 2; ++kk) {
      int k8r = kk * 4 + q;
      short8 af[4], bfv[4];
#pragma unroll
      for (int im = 0; im < 4; ++im) {
        int ml = wm * 64 + im * 16 + l15;
        af[im] = *(const short8*)&Als[(k8r * 128 + (ml ^ k8r)) * 8];
      }
#pragma unroll
      for (int in = 0; in < 4; ++in) {
        int nl = wn * 64 + in * 16 + l15;
        bfv[in] = *(const short8*)&Bls[(k8r * 128 + (nl ^ k8r)) * 8];
      }
#pragma unroll
      for (int im = 0; im < 4; ++im)
#pragma unroll
        for (int in = 0; in < 4; ++in)
          acc[im][in] = __builtin_amdgcn_mfma_f32_16x16x32_bf16(
              af[im], bfv[in], acc[im][in], 0, 0, 0);
    }
  }
  // epilogue: C/D layout col=lane&15, row=(lane>>4)*4+reg
#pragma unroll
  for (int im = 0; im < 4; ++im) {
    int row0 = mb * 128 + wm * 64 + im * 16 + q * 4;
#pragma unroll
    for (int in = 0; in < 4; ++in) {
      int col = nb * 128 + wn * 64 + in * 16 + l15;
      float bc = bias[col];
#pragma unroll
      for (int r = 0; r < 4; ++r) {
        float v = acc[im][in][r] + bc;
        xproj[(size_t)(row0 + r) * 4096 + col] = f2bf(v);
      }
    }
  }
}

// ---------------- recurrence: 128 persistent WGs, flag-pipelined --------------
// WG wg owns hidden units [wg*8, wg*8+8) -> 32 rows of Wh (i,f,g,o x 8), held in
// registers as B-fragments; K=1024 split across 8 waves (128 each).
__global__ __launch_bounds__(512) void lstm_rec(
    const float* __restrict__ Wh, const u16* __restrict__ xproj,
    const float* __restrict__ h0, const float* __restrict__ c0,
    float* __restrict__ out, u16* __restrict__ hbuf, int* __restrict__ flags) {
  __shared__ float pg[8][32][33];  // per-wave partial gates [wave][batch][n_local]
  __shared__ float cst[32][8];     // cell state fp32
  const int tid = threadIdx.x, lane = tid & 63, w = tid >> 6;
  const int hid0 = blockIdx.x * 8;
  const int ks = w * 128;
  const int bl = lane & 15, q = lane >> 4;

  // load Wh B-fragments into registers (once)
  short8 bfr[2][4];
#pragma unroll
  for (int ni = 0; ni < 2; ++ni) {
    int n_local = ni * 16 + bl;                       // 0..31 = g*8 + j
    int grow = (n_local >> 3) * 1024 + hid0 + (n_local & 7);
    const float* wp = Wh + (size_t)grow * 1024 + ks + q * 8;
#pragma unroll
    for (int kk = 0; kk < 4; ++kk) {
      short8 v;
#pragma unroll
      for (int j = 0; j < 8; ++j) v[j] = (short)f2bf(wp[kk * 32 + j]);
      bfr[ni][kk] = v;
    }
  }

  // init: h0 -> hbuf[0] (our slice), c0 -> LDS
  if (tid < 256) {
    int b = tid >> 3, j = tid & 7;
    cst[b][j] = c0[b * 1024 + hid0 + j];
    hbuf[b * 1024 + hid0 + j] = f2bf(h0[b * 1024 + hid0 + j]);
  }
  __threadfence();
  __syncthreads();
  if (tid == 0)
    __hip_atomic_fetch_add(&flags[0], 1, __ATOMIC_RELEASE, __HIP_MEMORY_SCOPE_AGENT);

  for (int t = 0; t < 512; ++t) {
    if (tid == 0) {
      while (__hip_atomic_load(&flags[t], __ATOMIC_RELAXED, __HIP_MEMORY_SCOPE_AGENT) < 128)
        __builtin_amdgcn_s_sleep(1);
    }
    __syncthreads();
    __threadfence();  // acquire: invalidate stale L1/L2 before reading h
    const u16* cur = hbuf + (t & 1) * 32768;
    u16* nxt = hbuf + ((t + 1) & 1) * 32768;

    // A-frags: h[b][k] for this wave's K-slice
    short8 af[2][4];
#pragma unroll
    for (int mi = 0; mi < 2; ++mi) {
      const u16* hp = cur + (size_t)(mi * 16 + bl) * 1024 + ks + q * 8;
#pragma unroll
      for (int kk = 0; kk < 4; ++kk) af[mi][kk] = *(const short8*)(hp + kk * 32);
    }
    f32x4 acc[2][2];
#pragma unroll
    for (int a = 0; a < 2; ++a)
#pragma unroll
      for (int b = 0; b < 2; ++b) acc[a][b] = {0.f, 0.f, 0.f, 0.f};
#pragma unroll
    for (int kk = 0; kk < 4; ++kk)
#pragma unroll
      for (int mi = 0; mi < 2; ++mi)
#pragma unroll
        for (int ni = 0; ni < 2; ++ni)
          acc[mi][ni] = __builtin_amdgcn_mfma_f32_16x16x32_bf16(
              af[mi][kk], bfr[ni][kk], acc[mi][ni], 0, 0, 0);
    // write K-partial results
#pragma unroll
    for (int mi = 0; mi < 2; ++mi)
#pragma unroll
      for (int ni = 0; ni < 2; ++ni)
#pragma unroll
        for (int r = 0; r < 4; ++r)
          pg[w][mi * 16 + q * 4 + r][ni * 16 + bl] = acc[mi][ni][r];
    __syncthreads();

    if (tid < 256) {
      int b = tid >> 3, j = tid & 7;
      float gi = 0.f, gf = 0.f, gg = 0.f, go = 0.f;
#pragma unroll
      for (int ww = 0; ww < 8; ++ww) {
        gi += pg[ww][b][j];
        gf += pg[ww][b][8 + j];
        gg += pg[ww][b][16 + j];
        go += pg[ww][b][24 + j];
      }
      const u16* xp = xproj + ((size_t)(t * 32 + b)) * 4096 + hid0 + j;
      gi += bf2f(xp[0]);
      gf += bf2f(xp[1024]);
      gg += bf2f(xp[2048]);
      go += bf2f(xp[3072]);
      float i_s = 1.f / (1.f + __expf(-gi));
      float f_s = 1.f / (1.f + __expf(-gf));
      float g_t = 1.f - 2.f / (__expf(2.f * gg) + 1.f);
      float o_s = 1.f / (1.f + __expf(-go));
      float c = f_s * cst[b][j] + i_s * g_t;
      cst[b][j] = c;
      float h = o_s * (1.f - 2.f / (__expf(2.f * c) + 1.f));
      out[(size_t)b * 524288 + (size_t)t * 1024 + hid0 + j] = h;
      nxt[b * 1024 + hid0 + j] = f2bf(h);
      if (t == 511) {
        out[16777216 + b * 1024 + hid0 + j] = h;          // h_T
        out[16777216 + 32768 + b * 1024 + hid0 + j] = c;  // c_T
      }
    }
    __threadfence();  // release our h slice
    __syncthreads();
    if (t < 511 && tid == 0)
      __hip_atomic_fetch_add(&flags[t + 1], 1, __ATOMIC_RELEASE, __HIP_MEMORY_SCOPE_AGENT);
  }
}

// ---------------- launch ------------------------------------------------------
extern "C" void kernel_launch(void* const* d_in, const int* in_sizes, int n_in,
                              void* d_out, int out_size, void* d_ws, size_t ws_size,
                              hipStream_t stream) {
  const float* x  = (const float*)d_in[0];
  const float* h0 = (const float*)d_in[1];
  const float* c0 = (const float*)d_in[2];
  const float* Wi = (const float*)d_in[3];
  const float* bi = (const float*)d_in[4];
  const float* Wh = (const float*)d_in[5];
  const float* bh = (const float*)d_in[6];
  float* out = (float*)d_out;

  // workspace layout (all 16B aligned)
  u16*   xbf   = (u16*)d_ws;                       // 33,554,432 B
  u16*   wibf  = xbf + NX;                         //  8,388,608 B
  float* bias  = (float*)(wibf + NWI);             //     16,384 B
  u16*   xproj = (u16*)(bias + 4096);              // 134,217,728 B
  u16*   hbuf  = xproj + (size_t)16384 * 4096;     //    131,072 B
  int*   flags = (int*)(hbuf + 2 * 32768);         //      4,096 B

  hipMemsetAsync(flags, 0, 4096, stream);
  prep_kernel<<<2048, 256, 0, stream>>>(x, Wi, bi, bh, xbf, wibf, bias);
  gemm_xproj<<<dim3(32, 128), 256, 0, stream>>>(xbf, wibf, bias, xproj);
  lstm_rec<<<128, 512, 0, stream>>>(Wh, xproj, h0, c0, out, hbuf, flags);
}

// Round 2
// 4497.157 us; speedup vs baseline: 5.1270x; 5.1270x over previous
//
#include <hip/hip_runtime.h>
#include <stdint.h>

typedef unsigned short u16;
typedef unsigned long long u64;
typedef __attribute__((ext_vector_type(8))) short short8;
typedef __attribute__((ext_vector_type(4))) float f32x4;

__device__ __forceinline__ u16 f2bf(float f) {
  union { float f; uint32_t u; } x; x.f = f;
  uint32_t u = x.u;
  uint32_t r = (u + 0x7fffu + ((u >> 16) & 1u)) >> 16;
  return (u16)r;
}
__device__ __forceinline__ float bf2f(u16 h) {
  union { uint32_t u; float f; } x; x.u = ((uint32_t)h) << 16;
  return x.f;
}

#define NX 16777216   // 32*512*1024
#define NWI 4194304   // 4096*1024

// ---------------- prep: fp32 -> bf16 for x, Wi; bias = bi + bh ----------------
__global__ __launch_bounds__(256) void prep_kernel(
    const float* __restrict__ x, const float* __restrict__ Wi,
    const float* __restrict__ bi, const float* __restrict__ bh,
    u16* __restrict__ xbf, u16* __restrict__ wibf, float* __restrict__ bias) {
  int tid = blockIdx.x * blockDim.x + threadIdx.x;
  int stride = gridDim.x * blockDim.x;
  const int nx4 = NX / 4, nw4 = NWI / 4;
  for (int i = tid; i < nx4 + nw4; i += stride) {
    float4 v = (i < nx4) ? ((const float4*)x)[i] : ((const float4*)Wi)[i - nx4];
    ushort4 o;
    o.x = f2bf(v.x); o.y = f2bf(v.y); o.z = f2bf(v.z); o.w = f2bf(v.w);
    if (i < nx4) ((ushort4*)xbf)[i] = o; else ((ushort4*)wibf)[i - nx4] = o;
  }
  for (int i = tid; i < 4096; i += stride) bias[i] = bi[i] + bh[i];
}

// ---------------- x_proj GEMM: D[m][n] = sum_k A[m][k]*Wi[n][k] + bias[n] -----
// m = t*32 + b  (xproj layout [T][B][4H], bf16 out)
__global__ __launch_bounds__(256) void gemm_xproj(
    const u16* __restrict__ xbf, const u16* __restrict__ wibf,
    const float* __restrict__ bias, u16* __restrict__ xproj) {
  __shared__ __align__(16) short Als[8192];  // 1024 16B chunks, [k8][m] XOR-swizzled
  __shared__ __align__(16) short Bls[8192];
  const int tid = threadIdx.x;
  const int lane = tid & 63;
  const int wv = tid >> 6;
  const int nb = blockIdx.x, mb = blockIdx.y;

  int offA[4], offB[4], ldsO[4];
#pragma unroll
  for (int i = 0; i < 4; ++i) {
    int s = i * 256 + tid;
    int m = s >> 3, k8 = s & 7;
    int mg = mb * 128 + m;                 // row of xproj = t*32+b
    offA[i] = ((mg & 31) * 512 + (mg >> 5)) * 1024 + k8 * 8;  // x[b][t][k8*8]
    int ng = nb * 128 + m;
    offB[i] = ng * 1024 + k8 * 8;
    ldsO[i] = (k8 * 128 + (m ^ k8)) * 8;
  }

  f32x4 acc[4][4];
#pragma unroll
  for (int a = 0; a < 4; ++a)
#pragma unroll
    for (int b = 0; b < 4; ++b) acc[a][b] = {0.f, 0.f, 0.f, 0.f};

  const int wm = wv >> 1, wn = wv & 1;
  const int q = lane >> 4, l15 = lane & 15;

  for (int k0 = 0; k0 < 1024; k0 += 64) {
    __syncthreads();
#pragma unroll
    for (int i = 0; i < 4; ++i) {
      short8 va = *(const short8*)(xbf + offA[i] + k0);
      short8 vb = *(const short8*)(wibf + offB[i] + k0);
      *(short8*)&Als[ldsO[i]] = va;
      *(short8*)&Bls[ldsO[i]] = vb;
    }
    __syncthreads();
#pragma unroll
    for (int kk = 0; kk < 2; ++kk) {
      int k8r = kk * 4 + q;
      short8 af[4], bfv[4];
#pragma unroll
      for (int im = 0; im < 4; ++im) {
        int ml = wm * 64 + im * 16 + l15;
        af[im] = *(const short8*)&Als[(k8r * 128 + (ml ^ k8r)) * 8];
      }
#pragma unroll
      for (int in = 0; in < 4; ++in) {
        int nl = wn * 64 + in * 16 + l15;
        bfv[in] = *(const short8*)&Bls[(k8r * 128 + (nl ^ k8r)) * 8];
      }
#pragma unroll
      for (int im = 0; im < 4; ++im)
#pragma unroll
        for (int in = 0; in < 4; ++in)
          acc[im][in] = __builtin_amdgcn_mfma_f32_16x16x32_bf16(
              af[im], bfv[in], acc[im][in], 0, 0, 0);
    }
  }
  // epilogue: C/D layout col=lane&15, row=(lane>>4)*4+reg
#pragma unroll
  for (int im = 0; im < 4; ++im) {
    int row0 = mb * 128 + wm * 64 + im * 16 + q * 4;
#pragma unroll
    for (int in = 0; in < 4; ++in) {
      int col = nb * 128 + wn * 64 + in * 16 + l15;
      float bc = bias[col];
#pragma unroll
      for (int r = 0; r < 4; ++r) {
        float v = acc[im][in][r] + bc;
        xproj[(size_t)(row0 + r) * 4096 + col] = f2bf(v);
      }
    }
  }
}

// ---------------- recurrence: 128 persistent WGs, fence-free flag pipeline ----
// WG wg owns hidden units [wg*8, wg*8+8) -> 32 rows of Wh, in registers as
// B-fragments (K split across 8 waves). Cross-WG h broadcast via agent-scope
// relaxed atomics (sc1, bypassing non-coherent L1/L2). Per-step arrival is a
// one-shot per-WG flag (plain sc1 store) -- NO fetch_add, NO threadfence:
// the 128-way serialized same-line RMW + L2 writeback walks were the 44us/step.
__global__ __launch_bounds__(512) void lstm_rec(
    const float* __restrict__ Wh, const u16* __restrict__ xproj,
    const float* __restrict__ h0, const float* __restrict__ c0,
    float* __restrict__ out, u64* __restrict__ hbuf, int* __restrict__ flags) {
  __shared__ float pg[8][32][33];  // per-wave partial gates [wave][batch][n_local]
  __shared__ float cst[32][8];     // cell state fp32
  __shared__ u16 hstage[256];      // h bf16 staging [b][j] for 8B packed stores
  const int tid = threadIdx.x, lane = tid & 63, w = tid >> 6;
  const int wg = blockIdx.x;
  const int hid0 = wg * 8;
  const int ks = w * 128;
  const int bl = lane & 15, q = lane >> 4;

  // load Wh B-fragments into registers (once)
  short8 bfr[2][4];
#pragma unroll
  for (int ni = 0; ni < 2; ++ni) {
    int n_local = ni * 16 + bl;                       // 0..31 = g*8 + j
    int grow = (n_local >> 3) * 1024 + hid0 + (n_local & 7);
    const float* wp = Wh + (size_t)grow * 1024 + ks + q * 8;
#pragma unroll
    for (int kk = 0; kk < 4; ++kk) {
      short8 v;
#pragma unroll
      for (int j = 0; j < 8; ++j) v[j] = (short)f2bf(wp[kk * 32 + j]);
      bfr[ni][kk] = v;
    }
  }

  // init: c0 -> LDS; h0 slice -> hbuf slot0 (sc1) ; then signal flags[0*128+wg]
  if (tid < 256) {
    int b = tid >> 3, j = tid & 7;
    cst[b][j] = c0[b * 1024 + hid0 + j];
    hstage[tid] = f2bf(h0[b * 1024 + hid0 + j]);
  }
  __syncthreads();
  if (tid < 64) {
    int b = tid >> 1, half = tid & 1;
    u64 v = ((const u64*)hstage)[tid];
    __hip_atomic_store(&hbuf[(b * 1024 + hid0 + half * 4) >> 2], v,
                       __ATOMIC_RELAXED, __HIP_MEMORY_SCOPE_AGENT);
    __builtin_amdgcn_s_waitcnt(0);  // store-ack at coherence point (wave 0 only)
    if (tid == 0)
      __hip_atomic_store(&flags[wg], 1, __ATOMIC_RELAXED, __HIP_MEMORY_SCOPE_AGENT);
  }

  for (int t = 0; t < 512; ++t) {
    // wait: parallel poll, one producer flag per thread (no serialized RMW)
    if (tid < 128) {
      int* fp = flags + t * 128 + tid;
      while (__hip_atomic_load(fp, __ATOMIC_RELAXED, __HIP_MEMORY_SCOPE_AGENT) == 0)
        __builtin_amdgcn_s_sleep(1);
    }
    __syncthreads();  // all waves held until h_t fully published

    u64* cur = hbuf + (size_t)(t & 1) * 8192;        // 8192 u64 = 64 KB slot
    u64* nxt = hbuf + (size_t)((t + 1) & 1) * 8192;

    // A-frags: h[b][k] for this wave's K-slice, sc1 loads (bypass stale L1/L2)
    short8 af[2][4];
#pragma unroll
    for (int mi = 0; mi < 2; ++mi) {
      int base16 = (mi * 16 + bl) * 1024 + ks + q * 8;
#pragma unroll
      for (int kk = 0; kk < 4; ++kk) {
        int i64 = (base16 + kk * 32) >> 2;
        union { short8 s; u64 d[2]; } u;
        u.d[0] = __hip_atomic_load(&cur[i64], __ATOMIC_RELAXED, __HIP_MEMORY_SCOPE_AGENT);
        u.d[1] = __hip_atomic_load(&cur[i64 + 1], __ATOMIC_RELAXED, __HIP_MEMORY_SCOPE_AGENT);
        af[mi][kk] = u.s;
      }
    }
    f32x4 acc[2][2];
#pragma unroll
    for (int a = 0; a < 2; ++a)
#pragma unroll
      for (int b = 0; b < 2; ++b) acc[a][b] = {0.f, 0.f, 0.f, 0.f};
#pragma unroll
    for (int kk = 0; kk < 4; ++kk)
#pragma unroll
      for (int mi = 0; mi < 2; ++mi)
#pragma unroll
        for (int ni = 0; ni < 2; ++ni)
          acc[mi][ni] = __builtin_amdgcn_mfma_f32_16x16x32_bf16(
              af[mi][kk], bfr[ni][kk], acc[mi][ni], 0, 0, 0);
    // write K-partial results
#pragma unroll
    for (int mi = 0; mi < 2; ++mi)
#pragma unroll
      for (int ni = 0; ni < 2; ++ni)
#pragma unroll
        for (int r = 0; r < 4; ++r)
          pg[w][mi * 16 + q * 4 + r][ni * 16 + bl] = acc[mi][ni][r];
    __syncthreads();

    if (tid < 256) {
      int b = tid >> 3, j = tid & 7;
      float gi = 0.f, gf = 0.f, gg = 0.f, go = 0.f;
#pragma unroll
      for (int ww = 0; ww < 8; ++ww) {
        gi += pg[ww][b][j];
        gf += pg[ww][b][8 + j];
        gg += pg[ww][b][16 + j];
        go += pg[ww][b][24 + j];
      }
      const u16* xp = xproj + ((size_t)(t * 32 + b)) * 4096 + hid0 + j;
      gi += bf2f(xp[0]);
      gf += bf2f(xp[1024]);
      gg += bf2f(xp[2048]);
      go += bf2f(xp[3072]);
      float i_s = 1.f / (1.f + __expf(-gi));
      float f_s = 1.f / (1.f + __expf(-gf));
      float g_t = 1.f - 2.f / (__expf(2.f * gg) + 1.f);
      float o_s = 1.f / (1.f + __expf(-go));
      float c = f_s * cst[b][j] + i_s * g_t;
      cst[b][j] = c;
      float h = o_s * (1.f - 2.f / (__expf(2.f * c) + 1.f));
      out[(size_t)b * 524288 + (size_t)t * 1024 + hid0 + j] = h;
      hstage[tid] = f2bf(h);
      if (t == 511) {
        out[16777216 + b * 1024 + hid0 + j] = h;          // h_T
        out[16777216 + 32768 + b * 1024 + hid0 + j] = c;  // c_T
      }
    }
    __syncthreads();  // hstage ready for packing

    // publish h slice (wave 0 only: stores + per-wave ack + flag, in order)
    if (t < 511 && tid < 64) {
      int b = tid >> 1, half = tid & 1;
      u64 v = ((const u64*)hstage)[tid];
      __hip_atomic_store(&nxt[(b * 1024 + hid0 + half * 4) >> 2], v,
                         __ATOMIC_RELAXED, __HIP_MEMORY_SCOPE_AGENT);
      __builtin_amdgcn_s_waitcnt(0);  // wave 0's stores acked globally
      if (tid == 0)
        __hip_atomic_store(&flags[(t + 1) * 128 + wg], 1,
                           __ATOMIC_RELAXED, __HIP_MEMORY_SCOPE_AGENT);
    }
    __syncthreads();  // keep hstage stable until packed
  }
}

// ---------------- launch ------------------------------------------------------
extern "C" void kernel_launch(void* const* d_in, const int* in_sizes, int n_in,
                              void* d_out, int out_size, void* d_ws, size_t ws_size,
                              hipStream_t stream) {
  const float* x  = (const float*)d_in[0];
  const float* h0 = (const float*)d_in[1];
  const float* c0 = (const float*)d_in[2];
  const float* Wi = (const float*)d_in[3];
  const float* bi = (const float*)d_in[4];
  const float* Wh = (const float*)d_in[5];
  const float* bh = (const float*)d_in[6];
  float* out = (float*)d_out;

  // workspace layout (all 16B aligned)
  u16*   xbf   = (u16*)d_ws;                       // 33,554,432 B
  u16*   wibf  = xbf + NX;                         //  8,388,608 B
  float* bias  = (float*)(wibf + NWI);             //     16,384 B
  u16*   xproj = (u16*)(bias + 4096);              // 134,217,728 B
  u64*   hbuf  = (u64*)(xproj + (size_t)16384 * 4096);  // 131,072 B (2 x 64KB)
  int*   flags = (int*)(hbuf + 2 * 8192);          //    262,144 B (512 steps x 128 WG)

  hipMemsetAsync(flags, 0, 512 * 128 * 4, stream);
  prep_kernel<<<2048, 256, 0, stream>>>(x, Wi, bi, bh, xbf, wibf, bias);
  gemm_xproj<<<dim3(32, 128), 256, 0, stream>>>(xbf, wibf, bias, xproj);
  lstm_rec<<<128, 512, 0, stream>>>(Wh, xproj, h0, c0, out, hbuf, flags);
}

// Round 3
// 3151.120 us; speedup vs baseline: 7.3170x; 1.4272x over previous
//
#include <hip/hip_runtime.h>
#include <stdint.h>

typedef unsigned short u16;
typedef unsigned long long u64;
typedef __attribute__((ext_vector_type(8))) short short8;
typedef __attribute__((ext_vector_type(4))) float f32x4;

__device__ __forceinline__ u16 f2bf(float f) {
  union { float f; uint32_t u; } x; x.f = f;
  uint32_t u = x.u;
  uint32_t r = (u + 0x7fffu + ((u >> 16) & 1u)) >> 16;
  return (u16)r;
}
__device__ __forceinline__ float bf2f(u16 h) {
  union { uint32_t u; float f; } x; x.u = ((uint32_t)h) << 16;
  return x.f;
}

#define NX 16777216   // 32*512*1024
#define NWI 4194304   // 4096*1024

// ---------------- prep: fp32 -> bf16 for x, Wi; bias = bi + bh ----------------
__global__ __launch_bounds__(256) void prep_kernel(
    const float* __restrict__ x, const float* __restrict__ Wi,
    const float* __restrict__ bi, const float* __restrict__ bh,
    u16* __restrict__ xbf, u16* __restrict__ wibf, float* __restrict__ bias) {
  int tid = blockIdx.x * blockDim.x + threadIdx.x;
  int stride = gridDim.x * blockDim.x;
  const int nx4 = NX / 4, nw4 = NWI / 4;
  for (int i = tid; i < nx4 + nw4; i += stride) {
    float4 v = (i < nx4) ? ((const float4*)x)[i] : ((const float4*)Wi)[i - nx4];
    ushort4 o;
    o.x = f2bf(v.x); o.y = f2bf(v.y); o.z = f2bf(v.z); o.w = f2bf(v.w);
    if (i < nx4) ((ushort4*)xbf)[i] = o; else ((ushort4*)wibf)[i - nx4] = o;
  }
  for (int i = tid; i < 4096; i += stride) bias[i] = bi[i] + bh[i];
}

// ---------------- x_proj GEMM: D[m][n] = sum_k A[m][k]*Wi[n][k] + bias[n] -----
// m = t*32 + b  (xproj layout [T][B][4H], bf16 out)
__global__ __launch_bounds__(256) void gemm_xproj(
    const u16* __restrict__ xbf, const u16* __restrict__ wibf,
    const float* __restrict__ bias, u16* __restrict__ xproj) {
  __shared__ __align__(16) short Als[8192];  // 1024 16B chunks, [k8][m] XOR-swizzled
  __shared__ __align__(16) short Bls[8192];
  const int tid = threadIdx.x;
  const int lane = tid & 63;
  const int wv = tid >> 6;
  const int nb = blockIdx.x, mb = blockIdx.y;

  int offA[4], offB[4], ldsO[4];
#pragma unroll
  for (int i = 0; i < 4; ++i) {
    int s = i * 256 + tid;
    int m = s >> 3, k8 = s & 7;
    int mg = mb * 128 + m;                 // row of xproj = t*32+b
    offA[i] = ((mg & 31) * 512 + (mg >> 5)) * 1024 + k8 * 8;  // x[b][t][k8*8]
    int ng = nb * 128 + m;
    offB[i] = ng * 1024 + k8 * 8;
    ldsO[i] = (k8 * 128 + (m ^ k8)) * 8;
  }

  f32x4 acc[4][4];
#pragma unroll
  for (int a = 0; a < 4; ++a)
#pragma unroll
    for (int b = 0; b < 4; ++b) acc[a][b] = {0.f, 0.f, 0.f, 0.f};

  const int wm = wv >> 1, wn = wv & 1;
  const int q = lane >> 4, l15 = lane & 15;

  for (int k0 = 0; k0 < 1024; k0 += 64) {
    __syncthreads();
#pragma unroll
    for (int i = 0; i < 4; ++i) {
      short8 va = *(const short8*)(xbf + offA[i] + k0);
      short8 vb = *(const short8*)(wibf + offB[i] + k0);
      *(short8*)&Als[ldsO[i]] = va;
      *(short8*)&Bls[ldsO[i]] = vb;
    }
    __syncthreads();
#pragma unroll
    for (int kk = 0; kk < 2; ++kk) {
      int k8r = kk * 4 + q;
      short8 af[4], bfv[4];
#pragma unroll
      for (int im = 0; im < 4; ++im) {
        int ml = wm * 64 + im * 16 + l15;
        af[im] = *(const short8*)&Als[(k8r * 128 + (ml ^ k8r)) * 8];
      }
#pragma unroll
      for (int in = 0; in < 4; ++in) {
        int nl = wn * 64 + in * 16 + l15;
        bfv[in] = *(const short8*)&Bls[(k8r * 128 + (nl ^ k8r)) * 8];
      }
#pragma unroll
      for (int im = 0; im < 4; ++im)
#pragma unroll
        for (int in = 0; in < 4; ++in)
          acc[im][in] = __builtin_amdgcn_mfma_f32_16x16x32_bf16(
              af[im], bfv[in], acc[im][in], 0, 0, 0);
    }
  }
  // epilogue: C/D layout col=lane&15, row=(lane>>4)*4+reg
#pragma unroll
  for (int im = 0; im < 4; ++im) {
    int row0 = mb * 128 + wm * 64 + im * 16 + q * 4;
#pragma unroll
    for (int in = 0; in < 4; ++in) {
      int col = nb * 128 + wn * 64 + in * 16 + l15;
      float bc = bias[col];
#pragma unroll
      for (int r = 0; r < 4; ++r) {
        float v = acc[im][in][r] + bc;
        xproj[(size_t)(row0 + r) * 4096 + col] = f2bf(v);
      }
    }
  }
}

// ---------------- recurrence: data-embedded epoch tags, zero flags ------------
// Each stored h bf16 donates its LSB as an epoch tag: tag(t) = ((t>>1)+1)&1.
// Double-buffered slots (parity of t) => consecutive same-slot epochs have
// opposite tags; tag(0)=1 differs from the 0xAA ws-poison (LSB=0); a producer
// s_waitcnt vmcnt(0) immediately before each publish bounds in-flight writes
// per slot to one epoch (kills the e-4 tag-alias hazard). Consumers retry-load
// exactly their MFMA A-fragments until tags match: detection = data arrival,
// one visibility hop, no flag traffic, no store-ack on the critical path.
__global__ __launch_bounds__(512) void lstm_rec(
    const float* __restrict__ Wh, const u16* __restrict__ xproj,
    const float* __restrict__ h0, const float* __restrict__ c0,
    float* __restrict__ out, u16* __restrict__ hbuf) {
  __shared__ float pg[8][32][36];  // stride 36: write(16q+bl) & read(4b+j+8g) <=2-way
  __shared__ float cst[32][8];     // cell state fp32
  const int tid = threadIdx.x, lane = tid & 63, w = tid >> 6;
  const int wg = blockIdx.x;
  const int hid0 = wg * 8;
  const int ks = w * 128;
  const int bl = lane & 15, q = lane >> 4;
  const int b = tid >> 3, j = tid & 7;   // epilogue coords (valid for tid<256)

  // load Wh B-fragments into registers (once)
  short8 bfr[2][4];
#pragma unroll
  for (int ni = 0; ni < 2; ++ni) {
    int n_local = ni * 16 + bl;                       // 0..31 = g*8 + j
    int grow = (n_local >> 3) * 1024 + hid0 + (n_local & 7);
    const float* wp = Wh + (size_t)grow * 1024 + ks + q * 8;
#pragma unroll
    for (int kk = 0; kk < 4; ++kk) {
      short8 v;
#pragma unroll
      for (int jj = 0; jj < 8; ++jj) v[jj] = (short)f2bf(wp[kk * 32 + jj]);
      bfr[ni][kk] = v;
    }
  }

  // init: c0 -> LDS; h0 slice published with tag 1 (epoch 0)
  if (tid < 256) {
    cst[b][j] = c0[b * 1024 + hid0 + j];
    u16 hv = (u16)((f2bf(h0[b * 1024 + hid0 + j]) & 0xFFFEu) | 1u);
    __hip_atomic_store(&hbuf[b * 1024 + hid0 + j], hv,
                       __ATOMIC_RELAXED, __HIP_MEMORY_SCOPE_AGENT);
  }

  // A-fragment u64 indices within a slot
  int aidx[2][4];
#pragma unroll
  for (int mi = 0; mi < 2; ++mi)
#pragma unroll
    for (int kk = 0; kk < 4; ++kk)
      aidx[mi][kk] = ((mi * 16 + bl) * 1024 + ks + q * 8 + kk * 32) >> 2;

  const u64 M = 0x0001000100010001ULL;

  for (int t = 0; t < 512; ++t) {
    const u64 E = (((t >> 1) + 1) & 1) ? M : 0ULL;
    const u64* cur = (const u64*)(hbuf + (t & 1) * 32768);
    u16* nxt = hbuf + ((t + 1) & 1) * 32768;

    // prefetch xproj gates early (independent of h)
    float xg0 = 0.f, xg1 = 0.f, xg2 = 0.f, xg3 = 0.f;
    if (tid < 256) {
      const u16* xp = xproj + ((size_t)(t * 32 + b)) * 4096 + hid0 + j;
      xg0 = bf2f(xp[0]); xg1 = bf2f(xp[1024]);
      xg2 = bf2f(xp[2048]); xg3 = bf2f(xp[3072]);
      asm volatile("" : "+v"(xg0), "+v"(xg1), "+v"(xg2), "+v"(xg3));  // keep issued here
    }

    // tag-verified retry load of exactly the needed A-fragments
    u64 d[2][4][2];
    bool ok = false;
    while (!ok) {
#pragma unroll
      for (int mi = 0; mi < 2; ++mi)
#pragma unroll
        for (int kk = 0; kk < 4; ++kk) {
          d[mi][kk][0] = __hip_atomic_load(&cur[aidx[mi][kk]],
                                           __ATOMIC_RELAXED, __HIP_MEMORY_SCOPE_AGENT);
          d[mi][kk][1] = __hip_atomic_load(&cur[aidx[mi][kk] + 1],
                                           __ATOMIC_RELAXED, __HIP_MEMORY_SCOPE_AGENT);
        }
      u64 bad = 0;
#pragma unroll
      for (int mi = 0; mi < 2; ++mi)
#pragma unroll
        for (int kk = 0; kk < 4; ++kk)
          bad |= ((d[mi][kk][0] ^ E) | (d[mi][kk][1] ^ E)) & M;
      ok = (bad == 0);
      if (!ok) __builtin_amdgcn_s_sleep(1);
    }

    f32x4 acc[2][2];
#pragma unroll
    for (int a = 0; a < 2; ++a)
#pragma unroll
      for (int bb = 0; bb < 2; ++bb) acc[a][bb] = {0.f, 0.f, 0.f, 0.f};
#pragma unroll
    for (int kk = 0; kk < 4; ++kk)
#pragma unroll
      for (int mi = 0; mi < 2; ++mi) {
        union { u64 dd[2]; short8 s; } u;
        u.dd[0] = d[mi][kk][0]; u.dd[1] = d[mi][kk][1];
#pragma unroll
        for (int ni = 0; ni < 2; ++ni)
          acc[mi][ni] = __builtin_amdgcn_mfma_f32_16x16x32_bf16(
              u.s, bfr[ni][kk], acc[mi][ni], 0, 0, 0);
      }
    // write K-partial results
#pragma unroll
    for (int mi = 0; mi < 2; ++mi)
#pragma unroll
      for (int ni = 0; ni < 2; ++ni)
#pragma unroll
        for (int r = 0; r < 4; ++r)
          pg[w][mi * 16 + q * 4 + r][ni * 16 + bl] = acc[mi][ni][r];
    __syncthreads();

    if (tid < 256) {
      float gi = 0.f, gf = 0.f, gg = 0.f, go = 0.f;
#pragma unroll
      for (int ww = 0; ww < 8; ++ww) {
        gi += pg[ww][b][j];
        gf += pg[ww][b][8 + j];
        gg += pg[ww][b][16 + j];
        go += pg[ww][b][24 + j];
      }
      gi += xg0; gf += xg1; gg += xg2; go += xg3;
      float i_s = 1.f / (1.f + __expf(-gi));
      float f_s = 1.f / (1.f + __expf(-gf));
      float g_t = 1.f - 2.f / (__expf(2.f * gg) + 1.f);
      float o_s = 1.f / (1.f + __expf(-go));
      float c = f_s * cst[b][j] + i_s * g_t;
      cst[b][j] = c;
      float h = o_s * (1.f - 2.f / (__expf(2.f * c) + 1.f));
      if (t < 511) {
        u16 ntag = (u16)((((t + 1) >> 1) + 1) & 1);
        u16 hv = (u16)((f2bf(h) & 0xFFFEu) | ntag);
        // bound in-flight writes per slot to one epoch before publishing
        asm volatile("s_waitcnt vmcnt(0)" ::: "memory");
        __hip_atomic_store(&nxt[b * 1024 + hid0 + j], hv,
                           __ATOMIC_RELAXED, __HIP_MEMORY_SCOPE_AGENT);
      }
      out[(size_t)b * 524288 + (size_t)t * 1024 + hid0 + j] = h;
      if (t == 511) {
        out[16777216 + b * 1024 + hid0 + j] = h;          // h_T
        out[16777216 + 32768 + b * 1024 + hid0 + j] = c;  // c_T
      }
    }
    __syncthreads();  // pg reused next iteration
  }
}

// ---------------- launch ------------------------------------------------------
extern "C" void kernel_launch(void* const* d_in, const int* in_sizes, int n_in,
                              void* d_out, int out_size, void* d_ws, size_t ws_size,
                              hipStream_t stream) {
  const float* x  = (const float*)d_in[0];
  const float* h0 = (const float*)d_in[1];
  const float* c0 = (const float*)d_in[2];
  const float* Wi = (const float*)d_in[3];
  const float* bi = (const float*)d_in[4];
  const float* Wh = (const float*)d_in[5];
  const float* bh = (const float*)d_in[6];
  float* out = (float*)d_out;

  // workspace layout (all 16B aligned)
  u16*   xbf   = (u16*)d_ws;                       // 33,554,432 B
  u16*   wibf  = xbf + NX;                         //  8,388,608 B
  float* bias  = (float*)(wibf + NWI);             //     16,384 B
  u16*   xproj = (u16*)(bias + 4096);              // 134,217,728 B
  u16*   hbuf  = xproj + (size_t)16384 * 4096;     //    131,072 B (2 x 64KB slots)

  prep_kernel<<<2048, 256, 0, stream>>>(x, Wi, bi, bh, xbf, wibf, bias);
  gemm_xproj<<<dim3(32, 128), 256, 0, stream>>>(xbf, wibf, bias, xproj);
  lstm_rec<<<128, 512, 0, stream>>>(Wh, xproj, h0, c0, out, hbuf);
}